// Round 5
// baseline (420.686 us; speedup 1.0000x reference)
//
#include <hip/hip_runtime.h>

// StochasticRegionalConvolution, NHWC-MFMA, full-line-write epilogue.
// out[b,co,p,q] = coeff(p,q) * sum_{ci,kh,kw} x[b,ci,p+kh,q+kw] * W[co,ci,kh,kw]
//
// K1: coeff map (256x256 f32)                     -> d_ws[0, 256KB)
// K2: weight transform to MFMA A-frag order, bf16 -> d_ws[256KB, 328KB)
// K3: x transform NCHW f32 -> NHWC bf16 (ci-minor)-> d_ws[1MB, 1MB+134MB)
// K4: conv, implicit GEMM, 16x32 pixel tile, 8 waves; writes are full 128B
//     lines (both 64B halves from the same wave, back-to-back).

typedef short short8 __attribute__((ext_vector_type(8)));
typedef float floatx4 __attribute__((ext_vector_type(4)));
typedef unsigned int uint4v __attribute__((ext_vector_type(4)));

#define OUTR 62

__device__ inline unsigned f2bf_pack(float lo, float hi) {
    unsigned ul = __builtin_bit_cast(unsigned, lo);
    unsigned uh = __builtin_bit_cast(unsigned, hi);
    ul = (ul + 0x7FFFu + ((ul >> 16) & 1u)) >> 16;   // RNE
    uh = (uh + 0x7FFFu + ((uh >> 16) & 1u)) >> 16;
    return ul | (uh << 16);
}

__global__ void srconv_coeff_kernel(const int* __restrict__ h_idx,
                                    const int* __restrict__ w_idx,
                                    const float* __restrict__ lam,
                                    int T, float* __restrict__ coeff) {
    int p = blockIdx.x;
    int q = threadIdx.x;
    float c = 0.f;
    for (int t = 0; t < T; ++t) {
        int dh = p - h_idx[t];
        int dw = q - w_idx[t];
        if (dh >= 0 && dh < OUTR && dw >= 0 && dw < OUTR) c += lam[t];
    }
    coeff[(p << 8) + q] = c * (1.0f / 16.0f);
}

__global__ void srconv_wtrans_kernel(const float* __restrict__ wgt,
                                     uint4v* __restrict__ afrag) {
    int id = blockIdx.x * 256 + threadIdx.x;      // [0, 72*64)
    int l  = id & 63;
    int fi = id >> 6;                             // (kk*2+cb)*4 + m
    int m  = fi & 3;
    int cb = (fi >> 2) & 1;
    int kk = fi >> 3;
    int co  = m * 16 + (l & 15);
    int ci0 = cb * 32 + (l >> 4) * 8;
    float w[8];
#pragma unroll
    for (int j = 0; j < 8; ++j)
        w[j] = wgt[(co * 64 + ci0 + j) * 9 + kk];
    uint4v d;
    d.x = f2bf_pack(w[0], w[1]);
    d.y = f2bf_pack(w[2], w[3]);
    d.z = f2bf_pack(w[4], w[5]);
    d.w = f2bf_pack(w[6], w[7]);
    afrag[id] = d;
}

// NCHW f32 -> NHWC bf16. Block: one (b, row, 64-col slab); LDS transpose.
__global__ void srconv_xtrans_kernel(const float* __restrict__ x,
                                     uint4v* __restrict__ xt) {
    __shared__ float xsf[64][65];
    const int t   = threadIdx.x;
    const int blk = blockIdx.x;                   // b*1024 + r*4 + cblk
    const int b   = blk >> 10;
    const int r   = (blk >> 2) & 255;
    const int C0  = (blk & 3) << 6;

#pragma unroll
    for (int it = 0; it < 4; ++it) {
        int u  = it * 256 + t;
        int ci = u >> 4;
        int c4 = (u & 15) << 2;
        const float4 v = *reinterpret_cast<const float4*>(
            x + (((b << 6) + ci) << 16) + (r << 8) + C0 + c4);
        xsf[ci][c4 + 0] = v.x;
        xsf[ci][c4 + 1] = v.y;
        xsf[ci][c4 + 2] = v.z;
        xsf[ci][c4 + 3] = v.w;
    }
    __syncthreads();
#pragma unroll
    for (int it = 0; it < 2; ++it) {
        int v   = it * 256 + t;
        int c   = v >> 3;
        int oct = v & 7;
        float w0 = xsf[oct * 8 + 0][c], w1 = xsf[oct * 8 + 1][c];
        float w2 = xsf[oct * 8 + 2][c], w3 = xsf[oct * 8 + 3][c];
        float w4 = xsf[oct * 8 + 4][c], w5 = xsf[oct * 8 + 5][c];
        float w6 = xsf[oct * 8 + 6][c], w7 = xsf[oct * 8 + 7][c];
        uint4v d;
        d.x = f2bf_pack(w0, w1);
        d.y = f2bf_pack(w2, w3);
        d.z = f2bf_pack(w4, w5);
        d.w = f2bf_pack(w6, w7);
        int pix = (((b << 8) + r) << 8) + C0 + c;
        xt[pix * 8 + oct] = d;
    }
}

// Conv from NHWC bf16. 16x32 pixel tile, 512 thr / 8 waves, no LDS.
// Wave wv: p-rows {2wv, 2wv+1}, all 32 q, all 64 co.
__launch_bounds__(512, 4)
__global__ void srconv_mfma_nhwc_kernel(const short8* __restrict__ xt,
                                        const float* __restrict__ coeff,
                                        const short8* __restrict__ afrag,
                                        float* __restrict__ out) {
    const int tid  = threadIdx.x;
    const int lane = tid & 63;
    const int wv   = tid >> 6;        // 0..7
    const int l15  = lane & 15;
    const int kg   = lane >> 4;

    const int tile = blockIdx.x;      // 16 p-tiles x 8 q-tiles
    const int b    = blockIdx.y;
    const int P0   = (tile >> 3) << 4;
    const int Q0   = (tile & 7) << 5;

    // ---- tile skip vote: 512 threads cover the 16x32 coeff tile ----
    float myc = coeff[((P0 + (tid >> 5)) << 8) + Q0 + (tid & 31)];
    if (__syncthreads_count(myc != 0.f) == 0) {
        // zero-fill with full-line float4 stores
        for (int u = tid; u < 64 * 16; u += 512) {
            int co = u >> 4, pr = u & 15;
            float4* op = (float4*)(out + (((b << 6) + co) << 16) +
                                   ((P0 + pr) << 8) + Q0);
#pragma unroll
            for (int j = 0; j < 8; ++j) op[j] = make_float4(0.f, 0.f, 0.f, 0.f);
        }
        return;
    }

    floatx4 acc[4][2][2];             // [m: co16][p: row][h: q-half]
#pragma unroll
    for (int m = 0; m < 4; ++m)
#pragma unroll
        for (int p = 0; p < 2; ++p)
#pragma unroll
            for (int h = 0; h < 2; ++h)
                acc[m][p][h] = (floatx4){0.f, 0.f, 0.f, 0.f};

    const int prb = P0 + (wv << 1);

#pragma unroll
    for (int kk = 0; kk < 9; ++kk) {
        const int kh = kk / 3;
        const int kw = kk - kh * 3;
        int rowbase[2];
#pragma unroll
        for (int p = 0; p < 2; ++p) {
            int pr = min(prb + p + kh, 255);
            rowbase[p] = (((b << 8) + pr) << 8) << 3;   // short8 units
        }
        int pcol[2];
#pragma unroll
        for (int h = 0; h < 2; ++h)
            pcol[h] = min(Q0 + (h << 4) + l15 + kw, 255) << 3;
#pragma unroll
        for (int cb = 0; cb < 2; ++cb) {
            short8 a[4];
#pragma unroll
            for (int m = 0; m < 4; ++m)
                a[m] = afrag[((((kk << 1) + cb) << 2) + m) * 64 + lane];
            short8 bf[2][2];
#pragma unroll
            for (int p = 0; p < 2; ++p)
#pragma unroll
                for (int h = 0; h < 2; ++h)
                    bf[p][h] = xt[rowbase[p] + pcol[h] + (cb << 2) + kg];
#pragma unroll
            for (int m = 0; m < 4; ++m)
#pragma unroll
                for (int p = 0; p < 2; ++p)
#pragma unroll
                    for (int h = 0; h < 2; ++h)
                        acc[m][p][h] = __builtin_amdgcn_mfma_f32_16x16x32_bf16(
                            a[m], bf[p][h], acc[m][p][h], 0, 0, 0);
        }
    }

    // ---- epilogue: coeff scale; h=0/h=1 stores adjacent -> full 128B lines
    // D layout (m89): col = lane&15 -> q, row = (lane>>4)*4+reg -> co
    float cf[2][2];
#pragma unroll
    for (int p = 0; p < 2; ++p)
#pragma unroll
        for (int h = 0; h < 2; ++h)
            cf[p][h] = coeff[((prb + p) << 8) + Q0 + (h << 4) + l15];

#pragma unroll
    for (int m = 0; m < 4; ++m)
#pragma unroll
        for (int p = 0; p < 2; ++p) {
            int rowoff = ((prb + p) << 8) + Q0 + l15;
#pragma unroll
            for (int reg = 0; reg < 4; ++reg) {
                int co = (m << 4) + (kg << 2) + reg;
                float* op = out + (((b << 6) + co) << 16) + rowoff;
                op[0]  = acc[m][p][0][reg] * cf[p][0];
                op[16] = acc[m][p][1][reg] * cf[p][1];
            }
        }
}

// ---------------- fallback (small d_ws): round-3 LDS-staged kernel ----------
__launch_bounds__(256, 2)
__global__ void srconv_mfma_lds_kernel(const float* __restrict__ x,
                                       const float* __restrict__ coeff,
                                       const short8* __restrict__ afrag,
                                       float* __restrict__ out) {
    __shared__ __align__(16) short xs[18 * 18 * 64];

    const int tid  = threadIdx.x;
    const int lane = tid & 63;
    const int wv   = tid >> 6;
    const int l15  = lane & 15;
    const int kg   = lane >> 4;
    const int tile = blockIdx.x;
    const int b    = blockIdx.y;
    const int P0   = (tile >> 4) << 4;
    const int Q0   = (tile & 15) << 4;

    float myc = coeff[((P0 + (tid >> 4)) << 8) + Q0 + (tid & 15)];
    if (__syncthreads_count(myc != 0.f) == 0) {
        int r = tid >> 4, c = tid & 15;
        float* op = out + ((b << 6) << 16) + ((P0 + r) << 8) + Q0 + c;
        for (int co = 0; co < 64; ++co) op[co << 16] = 0.f;
        return;
    }

    for (int idx = tid; idx < 8 * 18 * 18; idx += 256) {
        int cp8 = idx / (18 * 18);
        int rem = idx - cp8 * (18 * 18);
        int row = rem / 18;
        int col = rem - row * 18;
        int gr = min(P0 + row, 255);
        int gc = min(Q0 + col, 255);
        const float* xp = x + (((b << 6) + (cp8 << 3)) << 16) + (gr << 8) + gc;
        uint4v d;
        d.x = f2bf_pack(xp[0 << 16], xp[1 << 16]);
        d.y = f2bf_pack(xp[2 << 16], xp[3 << 16]);
        d.z = f2bf_pack(xp[4 << 16], xp[5 << 16]);
        d.w = f2bf_pack(xp[6 << 16], xp[7 << 16]);
        int off = ((row * 18 + col) << 6) + (cp8 << 3);
        off ^= (col & 7) << 3;
        *(uint4v*)(&xs[off]) = d;
    }
    __syncthreads();

    floatx4 acc[4][4];
#pragma unroll
    for (int m = 0; m < 4; ++m)
#pragma unroll
        for (int n = 0; n < 4; ++n) acc[m][n] = (floatx4){0.f, 0.f, 0.f, 0.f};

    const int w4 = wv << 2;
#pragma unroll
    for (int kk = 0; kk < 9; ++kk) {
        const int kh = kk / 3;
        const int kw = kk - kh * 3;
        const int col = kw + l15;
        const int cswz = (col & 7) << 3;
#pragma unroll
        for (int cb = 0; cb < 2; ++cb) {
            short8 a[4];
#pragma unroll
            for (int m = 0; m < 4; ++m)
                a[m] = afrag[((((kk << 1) + cb) << 2) + m) * 64 + lane];
            short8 bf[4];
#pragma unroll
            for (int n = 0; n < 4; ++n) {
                int lrow = w4 + n + kh;
                int off = (((lrow * 18 + col) << 6) + (cb << 5) + (kg << 3)) ^ cswz;
                bf[n] = *(const short8*)(&xs[off]);
            }
#pragma unroll
            for (int m = 0; m < 4; ++m)
#pragma unroll
                for (int n = 0; n < 4; ++n)
                    acc[m][n] = __builtin_amdgcn_mfma_f32_16x16x32_bf16(
                        a[m], bf[n], acc[m][n], 0, 0, 0);
        }
    }

#pragma unroll
    for (int n = 0; n < 4; ++n) {
        int pr = P0 + w4 + n;
        float cf = coeff[(pr << 8) + Q0 + l15];
#pragma unroll
        for (int m = 0; m < 4; ++m)
#pragma unroll
            for (int reg = 0; reg < 4; ++reg) {
                int co = (m << 4) + (kg << 2) + reg;
                out[(((b << 6) + co) << 16) + (pr << 8) + Q0 + l15] =
                    acc[m][n][reg] * cf;
            }
    }
}

extern "C" void kernel_launch(void* const* d_in, const int* in_sizes, int n_in,
                              void* d_out, int out_size, void* d_ws, size_t ws_size,
                              hipStream_t stream) {
    const float* x     = (const float*)d_in[0];
    const float* wgt   = (const float*)d_in[1];
    const int*   h_idx = (const int*)d_in[2];
    const int*   w_idx = (const int*)d_in[3];
    const float* lam   = (const float*)d_in[4];
    float*       out   = (float*)d_out;
    float*       coeff = (float*)d_ws;                        // 256 KB
    char*        af_b  = (char*)d_ws + 65536 * sizeof(float); // 72 KB
    const int    T     = in_sizes[2];

    const size_t xt_off   = 1u << 20;                         // 1 MB
    const size_t xt_bytes = (size_t)16 * 256 * 256 * 64 * 2;  // 134,217,728

    srconv_coeff_kernel<<<256, 256, 0, stream>>>(h_idx, w_idx, lam, T, coeff);
    srconv_wtrans_kernel<<<18, 256, 0, stream>>>(wgt, (uint4v*)af_b);

    if (ws_size >= xt_off + xt_bytes) {
        uint4v* xt = (uint4v*)((char*)d_ws + xt_off);
        srconv_xtrans_kernel<<<16384, 256, 0, stream>>>(x, xt);
        // grid: 16 p-tiles x 8 q-tiles = 128 tiles, x 16 batches
        srconv_mfma_nhwc_kernel<<<dim3(128, 16), 512, 0, stream>>>(
            (const short8*)xt, coeff, (const short8*)af_b, out);
    } else {
        srconv_mfma_lds_kernel<<<dim3(256, 16), 256, 0, stream>>>(
            x, coeff, (const short8*)af_b, out);
    }
}

// Round 7
// 401.614 us; speedup vs baseline: 1.0475x; 1.0475x over previous
//
#include <hip/hip_runtime.h>

// StochasticRegionalConvolution, NHWC-MFMA, full-line nt-store epilogue.
// out[b,co,p,q] = coeff(p,q) * sum_{ci,kh,kw} x[b,ci,p+kh,q+kw] * W[co,ci,kh,kw]
//
// K1: coeff map (256x256 f32)                     -> d_ws[0, 256KB)
// K2: weight transform to MFMA A-frag order, bf16 -> d_ws[256KB, 328KB)
// K3: x transform NCHW f32 -> NHWC bf16 (ci-minor)-> d_ws[1MB, 1MB+134MB)
// K4: conv, implicit GEMM, 16x32 tile, 8 waves; epilogue transposes each
//     wave's 16co x 32q acc slab through LDS and stores floatx4 per lane so
//     every store instruction covers 8 full 128B lines (nontemporal).

typedef short short8 __attribute__((ext_vector_type(8)));
typedef float floatx4 __attribute__((ext_vector_type(4)));
typedef unsigned int uint4v __attribute__((ext_vector_type(4)));

#define OUTR 62

__device__ inline unsigned f2bf_pack(float lo, float hi) {
    unsigned ul = __builtin_bit_cast(unsigned, lo);
    unsigned uh = __builtin_bit_cast(unsigned, hi);
    ul = (ul + 0x7FFFu + ((ul >> 16) & 1u)) >> 16;   // RNE
    uh = (uh + 0x7FFFu + ((uh >> 16) & 1u)) >> 16;
    return ul | (uh << 16);
}

__global__ void srconv_coeff_kernel(const int* __restrict__ h_idx,
                                    const int* __restrict__ w_idx,
                                    const float* __restrict__ lam,
                                    int T, float* __restrict__ coeff) {
    int p = blockIdx.x;
    int q = threadIdx.x;
    float c = 0.f;
    for (int t = 0; t < T; ++t) {
        int dh = p - h_idx[t];
        int dw = q - w_idx[t];
        if (dh >= 0 && dh < OUTR && dw >= 0 && dw < OUTR) c += lam[t];
    }
    coeff[(p << 8) + q] = c * (1.0f / 16.0f);
}

__global__ void srconv_wtrans_kernel(const float* __restrict__ wgt,
                                     uint4v* __restrict__ afrag) {
    int id = blockIdx.x * 256 + threadIdx.x;      // [0, 72*64)
    int l  = id & 63;
    int fi = id >> 6;                             // (kk*2+cb)*4 + m
    int m  = fi & 3;
    int cb = (fi >> 2) & 1;
    int kk = fi >> 3;
    int co  = m * 16 + (l & 15);
    int ci0 = cb * 32 + (l >> 4) * 8;
    float w[8];
#pragma unroll
    for (int j = 0; j < 8; ++j)
        w[j] = wgt[(co * 64 + ci0 + j) * 9 + kk];
    uint4v d;
    d.x = f2bf_pack(w[0], w[1]);
    d.y = f2bf_pack(w[2], w[3]);
    d.z = f2bf_pack(w[4], w[5]);
    d.w = f2bf_pack(w[6], w[7]);
    afrag[id] = d;
}

// NCHW f32 -> NHWC bf16. Block: one (b, row, 64-col slab); LDS transpose.
__global__ void srconv_xtrans_kernel(const float* __restrict__ x,
                                     uint4v* __restrict__ xt) {
    __shared__ float xsf[64][65];
    const int t   = threadIdx.x;
    const int blk = blockIdx.x;                   // b*1024 + r*4 + cblk
    const int b   = blk >> 10;
    const int r   = (blk >> 2) & 255;
    const int C0  = (blk & 3) << 6;

#pragma unroll
    for (int it = 0; it < 4; ++it) {
        int u  = it * 256 + t;
        int ci = u >> 4;
        int c4 = (u & 15) << 2;
        const float4 v = *reinterpret_cast<const float4*>(
            x + (((b << 6) + ci) << 16) + (r << 8) + C0 + c4);
        xsf[ci][c4 + 0] = v.x;
        xsf[ci][c4 + 1] = v.y;
        xsf[ci][c4 + 2] = v.z;
        xsf[ci][c4 + 3] = v.w;
    }
    __syncthreads();
#pragma unroll
    for (int it = 0; it < 2; ++it) {
        int v   = it * 256 + t;
        int c   = v >> 3;
        int oct = v & 7;
        float w0 = xsf[oct * 8 + 0][c], w1 = xsf[oct * 8 + 1][c];
        float w2 = xsf[oct * 8 + 2][c], w3 = xsf[oct * 8 + 3][c];
        float w4 = xsf[oct * 8 + 4][c], w5 = xsf[oct * 8 + 5][c];
        float w6 = xsf[oct * 8 + 6][c], w7 = xsf[oct * 8 + 7][c];
        uint4v d;
        d.x = f2bf_pack(w0, w1);
        d.y = f2bf_pack(w2, w3);
        d.z = f2bf_pack(w4, w5);
        d.w = f2bf_pack(w6, w7);
        int pix = (((b << 8) + r) << 8) + C0 + c;
        xt[pix * 8 + oct] = d;
    }
}

// Conv from NHWC bf16. 16x32 pixel tile, 512 thr / 8 waves.
// Wave wv: p-rows {2wv, 2wv+1}, all 32 q, all 64 co.
__launch_bounds__(512, 4)
__global__ void srconv_mfma_nhwc_kernel(const short8* __restrict__ xt,
                                        const float* __restrict__ coeff,
                                        const short8* __restrict__ afrag,
                                        float* __restrict__ out) {
    __shared__ float ep[8][16][36];   // per-wave transpose buffer (18,432 B)

    const int tid  = threadIdx.x;
    const int lane = tid & 63;
    const int wv   = tid >> 6;        // 0..7
    const int l15  = lane & 15;
    const int kg   = lane >> 4;

    // flattened grid + bijective XCD swizzle (2048 blocks, 8 XCDs, 256 each:
    // each XCD owns 2 full batches -> halo reuse stays in its L2)
    const unsigned bid = blockIdx.x;
    const unsigned swz = (bid & 7) * 256 + (bid >> 3);
    const int b    = swz >> 7;
    const int tile = swz & 127;       // 16 p-tiles x 8 q-tiles
    const int P0   = (tile >> 3) << 4;
    const int Q0   = (tile & 7) << 5;

    // ---- tile skip vote: 512 threads cover the 16x32 coeff tile ----
    float myc = coeff[((P0 + (tid >> 5)) << 8) + Q0 + (tid & 31)];
    if (__syncthreads_count(myc != 0.f) == 0) {
        // zero-fill: 8-lane groups write full 128B lines, nontemporal
        const floatx4 z = (floatx4){0.f, 0.f, 0.f, 0.f};
        for (int u = tid; u < 64 * 16 * 8; u += 512) {
            int q4 = u & 7;
            int pr = (u >> 3) & 15;
            int co = u >> 7;
            __builtin_nontemporal_store(
                z, (floatx4*)(out + (((b << 6) + co) << 16) +
                              ((P0 + pr) << 8) + Q0 + (q4 << 2)));
        }
        return;
    }

    floatx4 acc[4][2][2];             // [m: co16][p: row][h: q-half]
#pragma unroll
    for (int m = 0; m < 4; ++m)
#pragma unroll
        for (int p = 0; p < 2; ++p)
#pragma unroll
            for (int h = 0; h < 2; ++h)
                acc[m][p][h] = (floatx4){0.f, 0.f, 0.f, 0.f};

    const int prb = P0 + (wv << 1);

#pragma unroll
    for (int kk = 0; kk < 9; ++kk) {
        const int kh = kk / 3;
        const int kw = kk - kh * 3;
        int rowbase[2];
#pragma unroll
        for (int p = 0; p < 2; ++p) {
            int pr = min(prb + p + kh, 255);
            rowbase[p] = (((b << 8) + pr) << 8) << 3;   // short8 units
        }
        int pcol[2];
#pragma unroll
        for (int h = 0; h < 2; ++h)
            pcol[h] = min(Q0 + (h << 4) + l15 + kw, 255) << 3;
#pragma unroll
        for (int cb = 0; cb < 2; ++cb) {
            short8 a[4];
#pragma unroll
            for (int m = 0; m < 4; ++m)
                a[m] = afrag[((((kk << 1) + cb) << 2) + m) * 64 + lane];
            short8 bf[2][2];
#pragma unroll
            for (int p = 0; p < 2; ++p)
#pragma unroll
                for (int h = 0; h < 2; ++h)
                    bf[p][h] = xt[rowbase[p] + pcol[h] + (cb << 2) + kg];
#pragma unroll
            for (int m = 0; m < 4; ++m)
#pragma unroll
                for (int p = 0; p < 2; ++p)
#pragma unroll
                    for (int h = 0; h < 2; ++h)
                        acc[m][p][h] = __builtin_amdgcn_mfma_f32_16x16x32_bf16(
                            a[m], bf[p][h], acc[m][p][h], 0, 0, 0);
        }
    }

    // ---- epilogue: coeff-scale, per-wave LDS transpose, full-line nt stores
    // D layout (m89): col = lane&15 -> q, row = (lane>>4)*4+reg -> co-within-16
    float cf[2][2];
#pragma unroll
    for (int p = 0; p < 2; ++p)
#pragma unroll
        for (int h = 0; h < 2; ++h)
            cf[p][h] = coeff[((prb + p) << 8) + Q0 + (h << 4) + l15];

    const int co_l = lane >> 3;       // 0..7
    const int q4   = lane & 7;

#pragma unroll
    for (int p = 0; p < 2; ++p) {
        const int pr = prb + p;
#pragma unroll
        for (int m = 0; m < 4; ++m) {
#pragma unroll
            for (int h = 0; h < 2; ++h)
#pragma unroll
                for (int reg = 0; reg < 4; ++reg)
                    ep[wv][(kg << 2) + reg][(h << 4) + l15] =
                        acc[m][p][h][reg] * cf[p][h];
            __syncthreads();          // waits lgkmcnt(0) then barrier
#pragma unroll
            for (int j = 0; j < 2; ++j) {
                const floatx4 v = *reinterpret_cast<const floatx4*>(
                    &ep[wv][co_l + (j << 3)][q4 << 2]);
                const int co = (m << 4) + co_l + (j << 3);
                __builtin_nontemporal_store(
                    v, (floatx4*)(out + (((b << 6) + co) << 16) +
                                  (pr << 8) + Q0 + (q4 << 2)));
            }
            __syncthreads();          // reads done before next overwrite
        }
    }
}

// ---------------- fallback (small d_ws): round-3 LDS-staged kernel ----------
__launch_bounds__(256, 2)
__global__ void srconv_mfma_lds_kernel(const float* __restrict__ x,
                                       const float* __restrict__ coeff,
                                       const short8* __restrict__ afrag,
                                       float* __restrict__ out) {
    __shared__ __align__(16) short xs[18 * 18 * 64];

    const int tid  = threadIdx.x;
    const int lane = tid & 63;
    const int wv   = tid >> 6;
    const int l15  = lane & 15;
    const int kg   = lane >> 4;
    const int tile = blockIdx.x;
    const int b    = blockIdx.y;
    const int P0   = (tile >> 4) << 4;
    const int Q0   = (tile & 15) << 4;

    float myc = coeff[((P0 + (tid >> 4)) << 8) + Q0 + (tid & 15)];
    if (__syncthreads_count(myc != 0.f) == 0) {
        int r = tid >> 4, c = tid & 15;
        float* op = out + ((b << 6) << 16) + ((P0 + r) << 8) + Q0 + c;
        for (int co = 0; co < 64; ++co) op[co << 16] = 0.f;
        return;
    }

    for (int idx = tid; idx < 8 * 18 * 18; idx += 256) {
        int cp8 = idx / (18 * 18);
        int rem = idx - cp8 * (18 * 18);
        int row = rem / 18;
        int col = rem - row * 18;
        int gr = min(P0 + row, 255);
        int gc = min(Q0 + col, 255);
        const float* xp = x + (((b << 6) + (cp8 << 3)) << 16) + (gr << 8) + gc;
        uint4v d;
        d.x = f2bf_pack(xp[0 << 16], xp[1 << 16]);
        d.y = f2bf_pack(xp[2 << 16], xp[3 << 16]);
        d.z = f2bf_pack(xp[4 << 16], xp[5 << 16]);
        d.w = f2bf_pack(xp[6 << 16], xp[7 << 16]);
        int off = ((row * 18 + col) << 6) + (cp8 << 3);
        off ^= (col & 7) << 3;
        *(uint4v*)(&xs[off]) = d;
    }
    __syncthreads();

    floatx4 acc[4][4];
#pragma unroll
    for (int m = 0; m < 4; ++m)
#pragma unroll
        for (int n = 0; n < 4; ++n) acc[m][n] = (floatx4){0.f, 0.f, 0.f, 0.f};

    const int w4 = wv << 2;
#pragma unroll
    for (int kk = 0; kk < 9; ++kk) {
        const int kh = kk / 3;
        const int kw = kk - kh * 3;
        const int col = kw + l15;
        const int cswz = (col & 7) << 3;
#pragma unroll
        for (int cb = 0; cb < 2; ++cb) {
            short8 a[4];
#pragma unroll
            for (int m = 0; m < 4; ++m)
                a[m] = afrag[((((kk << 1) + cb) << 2) + m) * 64 + lane];
            short8 bf[4];
#pragma unroll
            for (int n = 0; n < 4; ++n) {
                int lrow = w4 + n + kh;
                int off = (((lrow * 18 + col) << 6) + (cb << 5) + (kg << 3)) ^ cswz;
                bf[n] = *(const short8*)(&xs[off]);
            }
#pragma unroll
            for (int m = 0; m < 4; ++m)
#pragma unroll
                for (int n = 0; n < 4; ++n)
                    acc[m][n] = __builtin_amdgcn_mfma_f32_16x16x32_bf16(
                        a[m], bf[n], acc[m][n], 0, 0, 0);
        }
    }

#pragma unroll
    for (int n = 0; n < 4; ++n) {
        int pr = P0 + w4 + n;
        float cf = coeff[(pr << 8) + Q0 + l15];
#pragma unroll
        for (int m = 0; m < 4; ++m)
#pragma unroll
            for (int reg = 0; reg < 4; ++reg) {
                int co = (m << 4) + (kg << 2) + reg;
                out[(((b << 6) + co) << 16) + (pr << 8) + Q0 + l15] =
                    acc[m][n][reg] * cf;
            }
    }
}

extern "C" void kernel_launch(void* const* d_in, const int* in_sizes, int n_in,
                              void* d_out, int out_size, void* d_ws, size_t ws_size,
                              hipStream_t stream) {
    const float* x     = (const float*)d_in[0];
    const float* wgt   = (const float*)d_in[1];
    const int*   h_idx = (const int*)d_in[2];
    const int*   w_idx = (const int*)d_in[3];
    const float* lam   = (const float*)d_in[4];
    float*       out   = (float*)d_out;
    float*       coeff = (float*)d_ws;                        // 256 KB
    char*        af_b  = (char*)d_ws + 65536 * sizeof(float); // 72 KB
    const int    T     = in_sizes[2];

    const size_t xt_off   = 1u << 20;                         // 1 MB
    const size_t xt_bytes = (size_t)16 * 256 * 256 * 64 * 2;  // 134,217,728

    srconv_coeff_kernel<<<256, 256, 0, stream>>>(h_idx, w_idx, lam, T, coeff);
    srconv_wtrans_kernel<<<18, 256, 0, stream>>>(wgt, (uint4v*)af_b);

    if (ws_size >= xt_off + xt_bytes) {
        uint4v* xt = (uint4v*)((char*)d_ws + xt_off);
        srconv_xtrans_kernel<<<16384, 256, 0, stream>>>(x, xt);
        // 2048 blocks = 128 tiles x 16 batches, flattened + XCD-swizzled
        srconv_mfma_nhwc_kernel<<<2048, 512, 0, stream>>>(
            (const short8*)xt, coeff, (const short8*)af_b, out);
    } else {
        srconv_mfma_lds_kernel<<<dim3(256, 16), 256, 0, stream>>>(
            x, coeff, (const short8*)af_b, out);
    }
}

// Round 8
// 278.855 us; speedup vs baseline: 1.5086x; 1.4402x over previous
//
#include <hip/hip_runtime.h>

// StochasticRegionalConvolution — fused single-pass MFMA conv.
// out[b,co,p,q] = coeff(p,q) * sum_{ci,kh,kw} x[b,ci,p+kh,q+kw] * W[co,ci,kh,kw]
//
// K1: coeff map (256x256 f32)                     -> d_ws[0, 256KB)
// K2: weight transform to MFMA A-frag order, bf16 -> d_ws[256KB, 328KB)
// K3: fused conv: per block 16x32 pixel tile, 512 thr / 8 waves.
//     x patch (18x34 pixels) staged NCHW->pixel-major bf16 LDS in two
//     ci-halves (acc persists in AGPRs across halves). B-frags via
//     conflict-free swizzled ds_read_b128; A-frags from global (L2-hot).
//     Epilogue: per-wave LDS transpose -> full-128B-line float4 stores.

typedef short short8 __attribute__((ext_vector_type(8)));
typedef float floatx4 __attribute__((ext_vector_type(4)));
typedef unsigned int uint4v __attribute__((ext_vector_type(4)));

#define OUTR 62

__device__ inline unsigned f2bf_pack(float lo, float hi) {
    unsigned ul = __builtin_bit_cast(unsigned, lo);
    unsigned uh = __builtin_bit_cast(unsigned, hi);
    ul = (ul + 0x7FFFu + ((ul >> 16) & 1u)) >> 16;   // RNE
    uh = (uh + 0x7FFFu + ((uh >> 16) & 1u)) >> 16;
    return ul | (uh << 16);
}

__global__ void srconv_coeff_kernel(const int* __restrict__ h_idx,
                                    const int* __restrict__ w_idx,
                                    const float* __restrict__ lam,
                                    int T, float* __restrict__ coeff) {
    int p = blockIdx.x;
    int q = threadIdx.x;
    float c = 0.f;
    for (int t = 0; t < T; ++t) {
        int dh = p - h_idx[t];
        int dw = q - w_idx[t];
        if (dh >= 0 && dh < OUTR && dw >= 0 && dw < OUTR) c += lam[t];
    }
    coeff[(p << 8) + q] = c * (1.0f / 16.0f);
}

__global__ void srconv_wtrans_kernel(const float* __restrict__ wgt,
                                     uint4v* __restrict__ afrag) {
    int id = blockIdx.x * 256 + threadIdx.x;      // [0, 72*64)
    int l  = id & 63;
    int fi = id >> 6;                             // (kk*2+cb)*4 + m
    int m  = fi & 3;
    int cb = (fi >> 2) & 1;
    int kk = fi >> 3;
    int co  = m * 16 + (l & 15);
    int ci0 = cb * 32 + (l >> 4) * 8;
    float w[8];
#pragma unroll
    for (int j = 0; j < 8; ++j)
        w[j] = wgt[(co * 64 + ci0 + j) * 9 + kk];
    uint4v d;
    d.x = f2bf_pack(w[0], w[1]);
    d.y = f2bf_pack(w[2], w[3]);
    d.z = f2bf_pack(w[4], w[5]);
    d.w = f2bf_pack(w[6], w[7]);
    afrag[id] = d;
}

// Fused conv. LDS x-patch layout: [pix = row*34+col][16 u32 of bf16 ci-pairs],
// u32 slot j holds ci-pair pr = j ^ ((pix>>1)&3)<<2  (2-bit XOR swizzle ->
// B-frag ds_read_b128 is bank-conflict-free; staging b32 writes ~8-way, rare).
__launch_bounds__(512, 4)
__global__ void srconv_fused_kernel(const float* __restrict__ x,
                                    const float* __restrict__ coeff,
                                    const short8* __restrict__ afrag,
                                    float* __restrict__ out) {
    __shared__ unsigned xs[612 * 16];     // 39,168 B
    __shared__ float ep[8][16][36];       // 18,432 B

    const int tid  = threadIdx.x;
    const int lane = tid & 63;
    const int wv   = tid >> 6;            // 0..7
    const int l15  = lane & 15;
    const int kg   = lane >> 4;

    // bijective XCD swizzle: 2048 blocks, 8 XCDs x 256 -> 2 batches per XCD
    const unsigned bid = blockIdx.x;
    const unsigned swz = (bid & 7) * 256 + (bid >> 3);
    const int b    = swz >> 7;
    const int tile = swz & 127;           // 16 p-tiles x 8 q-tiles
    const int P0   = (tile >> 3) << 4;
    const int Q0   = (tile & 7) << 5;

    // ---- tile skip vote ----
    float myc = coeff[((P0 + (tid >> 5)) << 8) + Q0 + (tid & 31)];
    if (__syncthreads_count(myc != 0.f) == 0) {
        const floatx4 z = (floatx4){0.f, 0.f, 0.f, 0.f};
        for (int u = tid; u < 64 * 16 * 8; u += 512) {
            int q4 = u & 7;
            int pr = (u >> 3) & 15;
            int co = u >> 7;
            *(floatx4*)(out + (((b << 6) + co) << 16) +
                        ((P0 + pr) << 8) + Q0 + (q4 << 2)) = z;
        }
        return;
    }

    floatx4 acc[4][2][2];                 // [m: co16][p: row][h: q-half]
#pragma unroll
    for (int m = 0; m < 4; ++m)
#pragma unroll
        for (int p = 0; p < 2; ++p)
#pragma unroll
            for (int h = 0; h < 2; ++h)
                acc[m][p][h] = (floatx4){0.f, 0.f, 0.f, 0.f};

    const float* xb  = x + ((size_t)(b << 6) << 16);
    const int    prb = P0 + (wv << 1);

    for (int cb = 0; cb < 2; ++cb) {
        __syncthreads();                  // prior pass's reads complete
        // ---- stage ci 32*cb..+31 as 16 bf16-pairs per pixel ----
#pragma unroll 4
        for (int pr = 0; pr < 16; ++pr) {
            const float* xp0 = xb + (((cb << 5) + (pr << 1)) << 16);
#pragma unroll
            for (int s = 0; s < 2; ++s) {
                int pix = (s << 9) + tid;
                if (pix < 612) {
                    int row = pix / 34;
                    int col = pix - row * 34;
                    int go  = (min(P0 + row, 255) << 8) + min(Q0 + col, 255);
                    unsigned v = f2bf_pack(xp0[go], xp0[65536 + go]);
                    xs[(pix << 4) + (pr ^ ((((pix >> 1) & 3)) << 2))] = v;
                }
            }
        }
        __syncthreads();

        // ---- compute: 9 taps, 16 MFMA each ----
#pragma unroll
        for (int kk = 0; kk < 9; ++kk) {
            const int kh = kk / 3;
            const int kw = kk - kh * 3;
            short8 a[4];
#pragma unroll
            for (int m = 0; m < 4; ++m)
                a[m] = afrag[((((kk << 1) + cb) << 2) + m) * 64 + lane];
            short8 bf[2][2];
#pragma unroll
            for (int p = 0; p < 2; ++p)
#pragma unroll
                for (int h = 0; h < 2; ++h) {
                    int prl = (wv << 1) + p + kh;          // 0..17
                    int cl  = (h << 4) + l15 + kw;         // 0..33
                    int pix = prl * 34 + cl;
                    int off = (pix << 4) +
                              ((kg << 2) ^ ((((pix >> 1) & 3)) << 2));
                    bf[p][h] = *(const short8*)(&xs[off]);
                }
#pragma unroll
            for (int m = 0; m < 4; ++m)
#pragma unroll
                for (int p = 0; p < 2; ++p)
#pragma unroll
                    for (int h = 0; h < 2; ++h)
                        acc[m][p][h] = __builtin_amdgcn_mfma_f32_16x16x32_bf16(
                            a[m], bf[p][h], acc[m][p][h], 0, 0, 0);
        }
    }

    // ---- epilogue: coeff-scale, per-wave LDS transpose, full-line stores
    // D layout (m89): col = lane&15 -> q, row = (lane>>4)*4+reg -> co-within-16
    float cf[2][2];
#pragma unroll
    for (int p = 0; p < 2; ++p)
#pragma unroll
        for (int h = 0; h < 2; ++h)
            cf[p][h] = coeff[((prb + p) << 8) + Q0 + (h << 4) + l15];

    const int co_l = lane >> 3;           // 0..7
    const int q4   = lane & 7;

#pragma unroll
    for (int p = 0; p < 2; ++p) {
        const int pr = prb + p;
#pragma unroll
        for (int m = 0; m < 4; ++m) {
#pragma unroll
            for (int h = 0; h < 2; ++h)
#pragma unroll
                for (int reg = 0; reg < 4; ++reg)
                    ep[wv][(kg << 2) + reg][(h << 4) + l15] =
                        acc[m][p][h][reg] * cf[p][h];
            __syncthreads();
#pragma unroll
            for (int j = 0; j < 2; ++j) {
                const floatx4 v = *reinterpret_cast<const floatx4*>(
                    &ep[wv][co_l + (j << 3)][q4 << 2]);
                const int co = (m << 4) + co_l + (j << 3);
                *(floatx4*)(out + (((b << 6) + co) << 16) +
                            (pr << 8) + Q0 + (q4 << 2)) = v;
            }
            __syncthreads();
        }
    }
}

extern "C" void kernel_launch(void* const* d_in, const int* in_sizes, int n_in,
                              void* d_out, int out_size, void* d_ws, size_t ws_size,
                              hipStream_t stream) {
    const float* x     = (const float*)d_in[0];
    const float* wgt   = (const float*)d_in[1];
    const int*   h_idx = (const int*)d_in[2];
    const int*   w_idx = (const int*)d_in[3];
    const float* lam   = (const float*)d_in[4];
    float*       out   = (float*)d_out;
    float*       coeff = (float*)d_ws;                        // 256 KB
    char*        af_b  = (char*)d_ws + 65536 * sizeof(float); // 72 KB
    const int    T     = in_sizes[2];

    srconv_coeff_kernel<<<256, 256, 0, stream>>>(h_idx, w_idx, lam, T, coeff);
    srconv_wtrans_kernel<<<18, 256, 0, stream>>>(wgt, (uint4v*)af_b);
    // 2048 blocks = 128 tiles x 16 batches, flattened + XCD-swizzled
    srconv_fused_kernel<<<2048, 512, 0, stream>>>(
        x, coeff, (const short8*)af_b, out);
}